// Round 8
// baseline (614.016 us; speedup 1.0000x reference)
//
#include <hip/hip_runtime.h>
#include <math.h>

#define IN_UNITS 1152
#define OUT_UNITS 32
#define BATCH 64
#define NCHK 24            // i-chunks; 24%8==0 -> chunk c on XCD c%8
#define IPB 48             // i's per chunk
#define NG 6               // i-groups per chunk (8 i x 32 o per group)
#define PREC 33            // values per (chunk,o): S, mu[16], v2[16]
#define PBLK (PREC*OUT_UNITS)   // 1056 floats, layout [j][o] (o-minor)

// W[i][o][ch] -> Wt[i][y][o][z] (ch=y*4+z). Output-coalesced one-time copy.
__global__ __launch_bounds__(256) void w_transpose(
    const float* __restrict__ W, float* __restrict__ Wt)
{
    const int gid = blockIdx.x*256 + threadIdx.x;   // 1152*512
    const int i = gid >> 9, rem = gid & 511;
    const int y = rem >> 7, o = (rem >> 2) & 31, z = rem & 3;
    Wt[gid] = W[i*512 + o*16 + y*4 + z];
}

// thread layout: t = il*32 + o (o=t&31, il=t>>5); lanes l,l^32 share o.
// MODE 0: stats under R = a/32.  MODE 1: R-update (softmax over o) + stats.
// Last-arriving block per b finalizes (threadfence reduction) -> no fin kernel.
template<int MODE>
__global__ __launch_bounds__(256, 4) void caps_main(
    const float* __restrict__ a_in, const float* __restrict__ Mm,
    const float4* __restrict__ Wt4,
    const float* __restrict__ mu_g, const float* __restrict__ i2v_g,
    const float* __restrict__ lae_g,
    float* __restrict__ part, unsigned int* __restrict__ cnt,
    float* __restrict__ mu_o, float* __restrict__ i2v_o, float* __restrict__ lae_o,
    const float* __restrict__ beta_u, const float* __restrict__ beta_a,
    float lamb, float* __restrict__ out)
{
    const int t = threadIdx.x, o = t & 31, il = t >> 5, wv = t >> 6, lane = t & 63;
    const int c = blockIdx.x, b = blockIdx.y, i0 = c*IPB;

    __shared__ float sRed[4][PBLK];   // 16.9 KB (stats reduce + fin reuse)
    __shared__ int sLast;

    // per-thread routing state for this o, in registers (no LDS, no barrier)
    float rmu[16], ri2[16], lae = 0.f;
    if (MODE) {
        #pragma unroll
        for (int k = 0; k < 16; ++k) {
            rmu[k] = mu_g[b*512 + k*32 + o];    // coalesced across o
            ri2[k] = i2v_g[b*512 + k*32 + o];
        }
        lae = lae_g[b*32 + o];                  // log a + log eff
    }

    const float4* wbase = Wt4 + (i0 + il)*128 + o;              // +g*1024 +y*32
    const float4* mbase = (const float4*)Mm + (b*IN_UNITS + i0 + il)*4;  // +g*32 +x
    const float*  abase = a_in + b*IN_UNITS + i0 + il;          // +g*8

    float pS = 0.f, pmu[16], pv2[16];
    #pragma unroll
    for (int k = 0; k < 16; ++k) { pmu[k] = 0.f; pv2[k] = 0.f; }

    #pragma unroll
    for (int g = 0; g < NG; ++g) {
        float w[16];
        #pragma unroll
        for (int y = 0; y < 4; ++y) *(float4*)&w[y*4] = wbase[g*1024 + y*32];
        float Mr[16];   // 64B row broadcast to 32 lanes via L1
        #pragma unroll
        for (int x = 0; x < 4; ++x) *(float4*)&Mr[x*4] = mbase[g*32 + x];
        const float a_val = abase[g*8];

        float v[16];
        #pragma unroll
        for (int x = 0; x < 4; ++x)
            #pragma unroll
            for (int z = 0; z < 4; ++z) {
                float acc = 0.f;
                #pragma unroll
                for (int y = 0; y < 4; ++y)
                    acc = fmaf(Mr[x*4 + y], w[y*4 + z], acc);
                v[x*4 + z] = acc;
            }

        float wgt;
        if (MODE == 0) {
            wgt = a_val * (1.0f/32.0f);          // R0 = 1/32
        } else {
            float ex0 = 0.f, ex1 = 0.f;
            #pragma unroll
            for (int k = 0; k < 16; k += 2) {
                float d0 = v[k]   - rmu[k];
                float d1 = v[k+1] - rmu[k+1];
                ex0 = fmaf(d0*d0, ri2[k],   ex0);
                ex1 = fmaf(d1*d1, ri2[k+1], ex1);
            }
            float e = __expf(lae - (ex0 + ex1)); // a*eff*exp(exponent)
            float s = e;
            #pragma unroll
            for (int m = 16; m >= 1; m >>= 1) s += __shfl_xor(s, m);
            wgt = (e / s) * a_val;               // R over o, * input_a
        }

        pS += wgt;
        #pragma unroll
        for (int k = 0; k < 16; ++k) {
            pmu[k] = fmaf(wgt, v[k], pmu[k]);
            pv2[k] = fmaf(wgt*v[k], v[k], pv2[k]);
        }
    }

    // lanes l <-> l^32 share o
    pS += __shfl_xor(pS, 32);
    #pragma unroll
    for (int k = 0; k < 16; ++k) {
        pmu[k] += __shfl_xor(pmu[k], 32);
        pv2[k] += __shfl_xor(pv2[k], 32);
    }
    if (lane < 32) {   // [j][o] layout: conflict-free, coalesced downstream
        float* r = &sRed[wv][0];
        r[o] = pS;
        #pragma unroll
        for (int k = 0; k < 16; ++k) {
            r[(1+k)*32 + o]  = pmu[k];
            r[(17+k)*32 + o] = pv2[k];
        }
    }
    __syncthreads();
    float* dst = part + (b*NCHK + c)*PBLK;
    for (int idx = t; idx < PBLK; idx += 256)
        dst[idx] = sRed[0][idx] + sRed[1][idx] + sRed[2][idx] + sRed[3][idx];

    // ---- threadfence reduction handoff: last block for this b finalizes ----
    __threadfence();            // release this thread's part writes (device scope)
    __syncthreads();            // all fences done before the count
    if (t == 0) {
        unsigned int old = atomicAdd(&cnt[b], 1u);
        sLast = (old == NCHK - 1);
    }
    __syncthreads();
    if (!sLast) return;
    __threadfence();            // acquire: see all blocks' part writes

    // finalize b: 8 segs x 3 chunks, fixed read order -> deterministic
    const int seg = wv*2 + ((lane >> 5) & 1);   // t>>5 in 0..7
    {
        float S = 0.f, m[16], q[16];
        #pragma unroll
        for (int k = 0; k < 16; ++k) { m[k] = 0.f; q[k] = 0.f; }
        #pragma unroll
        for (int cc = 0; cc < 3; ++cc) {
            const float* p = part + (b*NCHK + seg + cc*8)*PBLK;
            S += p[o];
            #pragma unroll
            for (int k = 0; k < 16; ++k) {
                m[k] += p[(1+k)*32 + o];
                q[k] += p[(17+k)*32 + o];
            }
        }
        __syncthreads();        // sRed free for reuse
        if (seg >= 4) {
            float* r = &sRed[seg-4][0];
            r[o] = S;
            #pragma unroll
            for (int k = 0; k < 16; ++k) { r[(1+k)*32+o] = m[k]; r[(17+k)*32+o] = q[k]; }
        }
        __syncthreads();
        if (seg < 4) {
            float* r = &sRed[seg][0];
            r[o] += S;
            #pragma unroll
            for (int k = 0; k < 16; ++k) { r[(1+k)*32+o] += m[k]; r[(17+k)*32+o] += q[k]; }
        }
        __syncthreads();
        if (t < 32) {
            S = 0.f;
            #pragma unroll
            for (int k = 0; k < 16; ++k) { m[k] = 0.f; q[k] = 0.f; }
            #pragma unroll
            for (int s = 0; s < 4; ++s) {
                const float* r = &sRed[s][0];
                S += r[o];
                #pragma unroll
                for (int k = 0; k < 16; ++k) { m[k] += r[(1+k)*32+o]; q[k] += r[(17+k)*32+o]; }
            }
            const float invS = 1.f / S;
            float mu[16], var[16], logvarsum = 0.f;
            #pragma unroll
            for (int k = 0; k < 16; ++k) {
                mu[k] = m[k] * invS;
                float vv = q[k]*invS - mu[k]*mu[k];   // E[v^2] - mu^2
                vv = fmaxf(vv, 1e-30f);
                var[k] = vv;
                logvarsum += logf(vv);
            }
            const float cost = S * (16.f*beta_u[o] + 0.5f*logvarsum);
            const float x = lamb * (beta_a[o] - cost);

            if (out) {   // last iteration: emit outputs only
                const int tid = b*32 + o;
                out[tid] = 1.f / (1.f + expf(-x));                      // a (64,32)
                #pragma unroll
                for (int k = 0; k < 16; ++k)
                    out[BATCH*OUT_UNITS + tid*16 + k] = mu[k];          // mu (64,32,16)
            } else {     // intermediate: emit routing state for next iteration
                const float log_a = (x >= 0.f) ? -log1pf(expf(-x)) : (x - log1pf(expf(x)));
                const float LOG2PI = 1.8378770664093453f;
                lae_o[b*32 + o] = log_a + 16.f*LOG2PI + logvarsum;
                #pragma unroll
                for (int k = 0; k < 16; ++k) {
                    mu_o[b*512 + k*32 + o]  = mu[k];
                    i2v_o[b*512 + k*32 + o] = 0.5f / var[k];
                }
            }
        }
    }
}

extern "C" void kernel_launch(void* const* d_in, const int* in_sizes, int n_in,
                              void* d_out, int out_size, void* d_ws, size_t ws_size,
                              hipStream_t stream)
{
    const float* a_in = (const float*)d_in[0];
    const float* Mm   = (const float*)d_in[1];
    const float* Wg   = (const float*)d_in[2];
    const float* bu   = (const float*)d_in[3];
    const float* ba   = (const float*)d_in[4];
    float* out = (float*)d_out;

    char* ws = (char*)d_ws;
    size_t off = 0;
    float* part  = (float*)(ws + off); off += (size_t)BATCH*NCHK*PBLK*sizeof(float);
    float* mu_g  = (float*)(ws + off); off += (size_t)BATCH*512*sizeof(float);
    float* i2v_g = (float*)(ws + off); off += (size_t)BATCH*512*sizeof(float);
    float* lae_g = (float*)(ws + off); off += (size_t)BATCH*32*sizeof(float);
    float* Wt    = (float*)(ws + off); off += (size_t)IN_UNITS*OUT_UNITS*16*sizeof(float);
    unsigned int* cnt = (unsigned int*)(ws + off); off += 3*BATCH*sizeof(unsigned int);

    hipMemsetAsync(cnt, 0, 3*BATCH*sizeof(unsigned int), stream);
    w_transpose<<<IN_UNITS*512/256, 256, 0, stream>>>(Wg, Wt);

    dim3 grid(NCHK, BATCH), blk(256);
    const float4* Wt4 = (const float4*)Wt;

    caps_main<0><<<grid, blk, 0, stream>>>(a_in, Mm, Wt4,
        nullptr, nullptr, nullptr, part, cnt + 0*BATCH,
        mu_g, i2v_g, lae_g, bu, ba, 0.01f, nullptr);
    caps_main<1><<<grid, blk, 0, stream>>>(a_in, Mm, Wt4,
        mu_g, i2v_g, lae_g, part, cnt + 1*BATCH,
        mu_g, i2v_g, lae_g, bu, ba, 0.012f, nullptr);
    caps_main<1><<<grid, blk, 0, stream>>>(a_in, Mm, Wt4,
        mu_g, i2v_g, lae_g, part, cnt + 2*BATCH,
        nullptr, nullptr, nullptr, bu, ba, 0.0144f, out);
}

// Round 9
// 240.628 us; speedup vs baseline: 2.5517x; 2.5517x over previous
//
#include <hip/hip_runtime.h>
#include <math.h>

#define IN_UNITS 1152
#define OUT_UNITS 32
#define BATCH 64
#define NCHK 24            // i-chunks; 24%8==0 -> chunk c on XCD c%8
#define IPB 48             // i's per chunk
#define NG 12              // g-steps per chunk; 4 i per step (1 per wave)
#define PREC 33            // values per (chunk,o): S, mu[16], v2[16]
#define PBLK (PREC*OUT_UNITS)   // 1056 floats, layout [j][o] (o-minor)

// channel k = x*4 + z, z = 2*zh + zz  ->  storage row  zh*8 + x*2 + zz
__device__ __forceinline__ int remap16(int k) {
    return ((k & 2) << 2) + ((k >> 2) << 1) + (k & 1);
}

// thread layout: o = t&31, zh = (t>>5)&1, wave wv = t>>6 owns i = i0+g*4+wv.
// Each thread handles 8 channels (its zh half). Softmax over o via shfl<=16;
// channel halves combined via shfl_xor(32).
// MODE 0: R = a/32; reads original W (float2, one-time strided), b==0 writes Wt2.
// MODE 1: R-update (softmax over o) + stats; reads Wt2 (coalesced).
template<int MODE>
__global__ __launch_bounds__(256, 4) void caps_main(
    const float* __restrict__ a_in, const float* __restrict__ Mm,
    const float* __restrict__ Wg, const float2* __restrict__ Wt2,
    float2* __restrict__ Wt2w,
    const float* __restrict__ mu_g, const float* __restrict__ i2v_g,
    const float* __restrict__ lae_g,
    float* __restrict__ part)
{
    const int t = threadIdx.x;
    const int o = t & 31;
    const int zh = (t >> 5) & 1;
    const int wv = t >> 6;
    const int c = blockIdx.x, b = blockIdx.y, i0 = c*IPB;

    __shared__ float sRed[4][PBLK];   // 16.9 KB

    // routing state for (b, o, this zh-half) in registers
    float rmu[8], ri2[8], lae = 0.f;
    if (MODE) {
        #pragma unroll
        for (int lk = 0; lk < 8; ++lk) {
            rmu[lk] = mu_g[b*512 + (zh*8 + lk)*32 + o];   // coalesced rows of 32
            ri2[lk] = i2v_g[b*512 + (zh*8 + lk)*32 + o];
        }
        lae = lae_g[b*32 + o];                            // log a + log eff
    }

    float pS = 0.f, pmu[8], pv2[8];
    #pragma unroll
    for (int lk = 0; lk < 8; ++lk) { pmu[lk] = 0.f; pv2[lk] = 0.f; }

    #pragma unroll
    for (int g = 0; g < NG; ++g) {
        const int i = i0 + g*4 + wv;

        float2 w2[4];   // W[i][o][y*4 + 2zh + zz], zz=0,1
        if (MODE == 0) {
            #pragma unroll
            for (int y = 0; y < 4; ++y)
                w2[y] = *(const float2*)(Wg + i*512 + o*16 + y*4 + zh*2);
            if (b == 0) {
                #pragma unroll
                for (int y = 0; y < 4; ++y)
                    Wt2w[(i*8 + y*2 + zh)*32 + o] = w2[y];   // coalesced
            }
        } else {
            #pragma unroll
            for (int y = 0; y < 4; ++y)
                w2[y] = Wt2[(i*8 + y*2 + zh)*32 + o];        // 512B/inst
        }
        const float a_val = a_in[b*IN_UNITS + i];            // wave-uniform

        float v[8];
        const float4* mrow = (const float4*)(Mm + (b*IN_UNITS + i)*16);
        #pragma unroll
        for (int x = 0; x < 4; ++x) {
            const float4 Mx = mrow[x];                       // wave-uniform bcast
            v[x*2+0] = fmaf(Mx.x, w2[0].x, fmaf(Mx.y, w2[1].x,
                       fmaf(Mx.z, w2[2].x, Mx.w*w2[3].x)));
            v[x*2+1] = fmaf(Mx.x, w2[0].y, fmaf(Mx.y, w2[1].y,
                       fmaf(Mx.z, w2[2].y, Mx.w*w2[3].y)));
        }

        float wgt;
        if (MODE == 0) {
            wgt = a_val * (1.0f/32.0f);          // R0 = 1/32
        } else {
            float ex0 = 0.f, ex1 = 0.f;
            #pragma unroll
            for (int lk = 0; lk < 8; lk += 2) {
                float d0 = v[lk]   - rmu[lk];
                float d1 = v[lk+1] - rmu[lk+1];
                ex0 = fmaf(d0*d0, ri2[lk],   ex0);
                ex1 = fmaf(d1*d1, ri2[lk+1], ex1);
            }
            float exh = ex0 + ex1;
            float ex = exh + __shfl_xor(exh, 32);   // combine channel halves
            float e = __expf(lae - ex);             // a*eff*exp(exponent)
            float s = e;
            #pragma unroll
            for (int m = 16; m >= 1; m >>= 1) s += __shfl_xor(s, m);
            wgt = (e / s) * a_val;                  // R over o, * input_a
        }

        pS += wgt;
        #pragma unroll
        for (int lk = 0; lk < 8; ++lk) {
            pmu[lk] = fmaf(wgt, v[lk], pmu[lk]);
            pv2[lk] = fmaf(wgt*v[lk], v[lk], pv2[lk]);
        }
    }

    // per-wave rows; zh halves write disjoint k rows (2-way bank alias = free)
    {
        float* r = &sRed[wv][0];
        if (zh == 0) r[o] = pS;
        #pragma unroll
        for (int lk = 0; lk < 8; ++lk) {
            const int k = (lk >> 1)*4 + zh*2 + (lk & 1);
            r[(1+k)*32 + o]  = pmu[lk];
            r[(17+k)*32 + o] = pv2[lk];
        }
    }
    __syncthreads();
    float* dst = part + (b*NCHK + c)*PBLK;
    for (int idx = t; idx < PBLK; idx += 256)
        dst[idx] = sRed[0][idx] + sRed[1][idx] + sRed[2][idx] + sRed[3][idx];
}

// finalize: one block per b reduces its 24 chunk-partials (seg handles 3)
__global__ __launch_bounds__(256) void caps_fin(
    const float* __restrict__ part,
    const float* __restrict__ beta_u, const float* __restrict__ beta_a,
    float* __restrict__ mu_g, float* __restrict__ i2v_g, float* __restrict__ lae_g,
    float lamb, float* __restrict__ out)
{
    const int b = blockIdx.x;
    const int t = threadIdx.x;
    const int o = t & 31;
    const int seg = t >> 5;

    float S = 0.f, m[16], q[16];
    #pragma unroll
    for (int k = 0; k < 16; ++k) { m[k] = 0.f; q[k] = 0.f; }
    #pragma unroll
    for (int cc = 0; cc < 3; ++cc) {
        const float* p = part + (b*NCHK + seg + cc*8)*PBLK;
        S += p[o];
        #pragma unroll
        for (int k = 0; k < 16; ++k) {
            m[k] += p[(1+k)*32 + o];
            q[k] += p[(17+k)*32 + o];
        }
    }

    __shared__ float sF[8][PBLK];
    {
        float* r = &sF[seg][0];
        r[o] = S;
        #pragma unroll
        for (int k = 0; k < 16; ++k) { r[(1+k)*32+o] = m[k]; r[(17+k)*32+o] = q[k]; }
    }
    __syncthreads();
    if (t < 32) {
        #pragma unroll
        for (int s = 1; s < 8; ++s) {
            const float* r = &sF[s][0];
            S += r[o];
            #pragma unroll
            for (int k = 0; k < 16; ++k) { m[k] += r[(1+k)*32+o]; q[k] += r[(17+k)*32+o]; }
        }
        const float invS = 1.f / S;
        float mu[16], var[16], logvarsum = 0.f;
        #pragma unroll
        for (int k = 0; k < 16; ++k) {
            mu[k] = m[k] * invS;
            float vv = q[k]*invS - mu[k]*mu[k];   // E[v^2] - mu^2
            vv = fmaxf(vv, 1e-30f);
            var[k] = vv;
            logvarsum += logf(vv);
        }
        const float cost = S * (16.f*beta_u[o] + 0.5f*logvarsum);
        const float x = lamb * (beta_a[o] - cost);
        const float log_a = (x >= 0.f) ? -log1pf(expf(-x)) : (x - log1pf(expf(x)));
        const float LOG2PI = 1.8378770664093453f;
        const float logeff = 16.f*LOG2PI + logvarsum;

        const int tid = b*32 + o;
        lae_g[tid] = log_a + logeff;
        #pragma unroll
        for (int k = 0; k < 16; ++k) {
            mu_g[b*512 + remap16(k)*32 + o]  = mu[k];     // z-split layout
            i2v_g[b*512 + remap16(k)*32 + o] = 0.5f / var[k];
        }
        if (out) {
            out[tid] = 1.f / (1.f + expf(-x));                      // a (64,32)
            #pragma unroll
            for (int k = 0; k < 16; ++k)
                out[BATCH*OUT_UNITS + tid*16 + k] = mu[k];          // mu (64,32,16)
        }
    }
}

extern "C" void kernel_launch(void* const* d_in, const int* in_sizes, int n_in,
                              void* d_out, int out_size, void* d_ws, size_t ws_size,
                              hipStream_t stream)
{
    const float* a_in = (const float*)d_in[0];
    const float* Mm   = (const float*)d_in[1];
    const float* Wg   = (const float*)d_in[2];
    const float* bu   = (const float*)d_in[3];
    const float* ba   = (const float*)d_in[4];
    float* out = (float*)d_out;

    char* ws = (char*)d_ws;
    size_t off = 0;
    float* part  = (float*)(ws + off); off += (size_t)BATCH*NCHK*PBLK*sizeof(float);
    float* mu_g  = (float*)(ws + off); off += (size_t)BATCH*512*sizeof(float);
    float* i2v_g = (float*)(ws + off); off += (size_t)BATCH*512*sizeof(float);
    float* lae_g = (float*)(ws + off); off += (size_t)BATCH*32*sizeof(float);
    float* Wt    = (float*)(ws + off); off += (size_t)IN_UNITS*OUT_UNITS*16*sizeof(float);

    dim3 grid(NCHK, BATCH), blk(256);
    const float2* Wt2 = (const float2*)Wt;
    float2* Wt2w = (float2*)Wt;

    // it 0 (reads original W, emits Wt2 from b==0 blocks)
    caps_main<0><<<grid, blk, 0, stream>>>(a_in, Mm, Wg, nullptr, Wt2w,
                                           nullptr, nullptr, nullptr, part);
    caps_fin<<<BATCH, 256, 0, stream>>>(part, bu, ba, mu_g, i2v_g, lae_g, 0.01f, nullptr);
    // it 1
    caps_main<1><<<grid, blk, 0, stream>>>(a_in, Mm, nullptr, Wt2, nullptr,
                                           mu_g, i2v_g, lae_g, part);
    caps_fin<<<BATCH, 256, 0, stream>>>(part, bu, ba, mu_g, i2v_g, lae_g, 0.012f, nullptr);
    // it 2
    caps_main<1><<<grid, blk, 0, stream>>>(a_in, Mm, nullptr, Wt2, nullptr,
                                           mu_g, i2v_g, lae_g, part);
    caps_fin<<<BATCH, 256, 0, stream>>>(part, bu, ba, mu_g, i2v_g, lae_g, 0.0144f, out);
}

// Round 10
// 87.809 us; speedup vs baseline: 6.9926x; 2.7404x over previous
//
#include <hip/hip_runtime.h>
#include <math.h>

#define IN_UNITS 1152
#define OUT_UNITS 32
#define BATCH 64
#define NCHK 24            // i-chunks; 24%8==0 -> chunk c on XCD c%8
#define IPB 48             // i's per chunk
#define NG 6               // i-groups per chunk (8 i x 32 o per group)
#define PREC 33            // values per (chunk,o): S, mu[16], v2[16]
#define PBLK (PREC*OUT_UNITS)   // 1056 floats, layout [j][o] (o-minor)

// W[i][o][ch] -> Wt[i][y][o][z] (ch=y*4+z). Output-coalesced one-time copy.
__global__ __launch_bounds__(256) void w_transpose(
    const float* __restrict__ W, float* __restrict__ Wt)
{
    const int gid = blockIdx.x*256 + threadIdx.x;   // 1152*512
    const int i = gid >> 9, rem = gid & 511;
    const int y = rem >> 7, o = (rem >> 2) & 31, z = rem & 3;
    Wt[gid] = W[i*512 + o*16 + y*4 + z];
}

// thread layout: t = il*32 + o (o=t&31, il=t>>5); lanes l,l^32 share o.
// MODE 0: stats under R = a/32.
// MODE 1: redundant per-block finalize of part_in (fixed order -> deterministic,
//         no fences: visibility via kernel boundary) + R-update + stats.
template<int MODE>
__global__ __launch_bounds__(256, 4) void caps_main(
    const float* __restrict__ a_in, const float* __restrict__ Mm,
    const float4* __restrict__ Wt4,
    const float* __restrict__ part_in,
    const float* __restrict__ beta_u, const float* __restrict__ beta_a,
    float lamb,
    float* __restrict__ part_out)
{
    const int t = threadIdx.x, o = t & 31, il = t >> 5, wv = t >> 6, lane = t & 63;
    const int c = blockIdx.x, b = blockIdx.y, i0 = c*IPB;

    __shared__ float sRed[4][PBLK];   // 16.9 KB

    // per-thread routing state for this o, in registers
    float rmu[16], ri2[16], lae = 0.f;
    if (MODE) {
        // ---- phase A: 8 segs x 3 chunks partial reduction of part_in[b] ----
        const int seg = t >> 5;
        float S = 0.f, m[16], q[16];
        #pragma unroll
        for (int k = 0; k < 16; ++k) { m[k] = 0.f; q[k] = 0.f; }
        #pragma unroll
        for (int cc = 0; cc < 3; ++cc) {
            const float* p = part_in + (b*NCHK + seg + cc*8)*PBLK;
            S += p[o];
            #pragma unroll
            for (int k = 0; k < 16; ++k) {
                m[k] += p[(1+k)*32 + o];
                q[k] += p[(17+k)*32 + o];
            }
        }
        // ---- phase B: 8 -> 4 rows in LDS ----
        if (seg >= 4) {
            float* r = &sRed[seg-4][0];
            r[o] = S;
            #pragma unroll
            for (int k = 0; k < 16; ++k) { r[(1+k)*32+o] = m[k]; r[(17+k)*32+o] = q[k]; }
        }
        __syncthreads();
        if (seg < 4) {
            float* r = &sRed[seg][0];
            r[o] += S;
            #pragma unroll
            for (int k = 0; k < 16; ++k) { r[(1+k)*32+o] += m[k]; r[(17+k)*32+o] += q[k]; }
        }
        __syncthreads();
        // ---- phase C: lanes t<32 combine 4 rows, compute routing state ----
        if (t < 32) {
            S = 0.f;
            #pragma unroll
            for (int k = 0; k < 16; ++k) { m[k] = 0.f; q[k] = 0.f; }
            #pragma unroll
            for (int s = 0; s < 4; ++s) {
                const float* r = &sRed[s][0];
                S += r[o];
                #pragma unroll
                for (int k = 0; k < 16; ++k) { m[k] += r[(1+k)*32+o]; q[k] += r[(17+k)*32+o]; }
            }
            const float invS = 1.f / S;
            float mu[16], logvarsum = 0.f;
            #pragma unroll
            for (int k = 0; k < 16; ++k) {
                mu[k] = m[k] * invS;
                float vv = q[k]*invS - mu[k]*mu[k];   // E[v^2] - mu^2
                vv = fmaxf(vv, 1e-30f);
                q[k] = vv;                            // var
                logvarsum += logf(vv);
            }
            const float cost = S * (16.f*beta_u[o] + 0.5f*logvarsum);
            const float x = lamb * (beta_a[o] - cost);
            const float log_a = (x >= 0.f) ? -log1pf(expf(-x)) : (x - log1pf(expf(x)));
            const float LOG2PI = 1.8378770664093453f;
            // stage into sRed[0]: lae at j=0, mu at j=1..16, i2v at j=17..32
            float* r0 = &sRed[0][0];
            r0[o] = log_a + 16.f*LOG2PI + logvarsum;
            #pragma unroll
            for (int k = 0; k < 16; ++k) {
                r0[(1+k)*32 + o]  = mu[k];
                r0[(17+k)*32 + o] = 0.5f / q[k];
            }
        }
        __syncthreads();
        // ---- phase D: everyone loads its o's routing state ----
        lae = sRed[0][o];
        #pragma unroll
        for (int k = 0; k < 16; ++k) {
            rmu[k] = sRed[0][(1+k)*32 + o];
            ri2[k] = sRed[0][(17+k)*32 + o];
        }
        __syncthreads();   // sRed free for the stats reduce
    }

    const float4* wbase = Wt4 + (i0 + il)*128 + o;              // +g*1024 +y*32
    const float4* mbase = (const float4*)Mm + (b*IN_UNITS + i0 + il)*4;  // +g*32 +x
    const float*  abase = a_in + b*IN_UNITS + i0 + il;          // +g*8

    float pS = 0.f, pmu[16], pv2[16];
    #pragma unroll
    for (int k = 0; k < 16; ++k) { pmu[k] = 0.f; pv2[k] = 0.f; }

    #pragma unroll
    for (int g = 0; g < NG; ++g) {
        float w[16];
        #pragma unroll
        for (int y = 0; y < 4; ++y) *(float4*)&w[y*4] = wbase[g*1024 + y*32];
        float Mr[16];   // 64B row broadcast to 32 lanes via L1
        #pragma unroll
        for (int x = 0; x < 4; ++x) *(float4*)&Mr[x*4] = mbase[g*32 + x];
        const float a_val = abase[g*8];

        float v[16];
        #pragma unroll
        for (int x = 0; x < 4; ++x)
            #pragma unroll
            for (int z = 0; z < 4; ++z) {
                float acc = 0.f;
                #pragma unroll
                for (int y = 0; y < 4; ++y)
                    acc = fmaf(Mr[x*4 + y], w[y*4 + z], acc);
                v[x*4 + z] = acc;
            }

        float wgt;
        if (MODE == 0) {
            wgt = a_val * (1.0f/32.0f);          // R0 = 1/32
        } else {
            float ex0 = 0.f, ex1 = 0.f;
            #pragma unroll
            for (int k = 0; k < 16; k += 2) {
                float d0 = v[k]   - rmu[k];
                float d1 = v[k+1] - rmu[k+1];
                ex0 = fmaf(d0*d0, ri2[k],   ex0);
                ex1 = fmaf(d1*d1, ri2[k+1], ex1);
            }
            float e = __expf(lae - (ex0 + ex1)); // a*eff*exp(exponent)
            float s = e;
            #pragma unroll
            for (int m = 16; m >= 1; m >>= 1) s += __shfl_xor(s, m);
            wgt = (e / s) * a_val;               // R over o, * input_a
        }

        pS += wgt;
        #pragma unroll
        for (int k = 0; k < 16; ++k) {
            pmu[k] = fmaf(wgt, v[k], pmu[k]);
            pv2[k] = fmaf(wgt*v[k], v[k], pv2[k]);
        }
    }

    // lanes l <-> l^32 share o
    pS += __shfl_xor(pS, 32);
    #pragma unroll
    for (int k = 0; k < 16; ++k) {
        pmu[k] += __shfl_xor(pmu[k], 32);
        pv2[k] += __shfl_xor(pv2[k], 32);
    }
    if (lane < 32) {   // [j][o] layout: conflict-free, coalesced downstream
        float* r = &sRed[wv][0];
        r[o] = pS;
        #pragma unroll
        for (int k = 0; k < 16; ++k) {
            r[(1+k)*32 + o]  = pmu[k];
            r[(17+k)*32 + o] = pv2[k];
        }
    }
    __syncthreads();
    float* dst = part_out + (b*NCHK + c)*PBLK;
    for (int idx = t; idx < PBLK; idx += 256)
        dst[idx] = sRed[0][idx] + sRed[1][idx] + sRed[2][idx] + sRed[3][idx];
}

// final output: one block per b reduces its 24 chunk-partials, writes a & mu
__global__ __launch_bounds__(256) void caps_out(
    const float* __restrict__ part,
    const float* __restrict__ beta_u, const float* __restrict__ beta_a,
    float lamb, float* __restrict__ out)
{
    const int b = blockIdx.x;
    const int t = threadIdx.x;
    const int o = t & 31;
    const int seg = t >> 5;

    float S = 0.f, m[16], q[16];
    #pragma unroll
    for (int k = 0; k < 16; ++k) { m[k] = 0.f; q[k] = 0.f; }
    #pragma unroll
    for (int cc = 0; cc < 3; ++cc) {
        const float* p = part + (b*NCHK + seg + cc*8)*PBLK;
        S += p[o];
        #pragma unroll
        for (int k = 0; k < 16; ++k) {
            m[k] += p[(1+k)*32 + o];
            q[k] += p[(17+k)*32 + o];
        }
    }

    __shared__ float sF[8][PBLK];
    {
        float* r = &sF[seg][0];
        r[o] = S;
        #pragma unroll
        for (int k = 0; k < 16; ++k) { r[(1+k)*32+o] = m[k]; r[(17+k)*32+o] = q[k]; }
    }
    __syncthreads();
    if (t < 32) {
        #pragma unroll
        for (int s = 1; s < 8; ++s) {
            const float* r = &sF[s][0];
            S += r[o];
            #pragma unroll
            for (int k = 0; k < 16; ++k) { m[k] += r[(1+k)*32+o]; q[k] += r[(17+k)*32+o]; }
        }
        const float invS = 1.f / S;
        float mu[16], logvarsum = 0.f;
        #pragma unroll
        for (int k = 0; k < 16; ++k) {
            mu[k] = m[k] * invS;
            float vv = q[k]*invS - mu[k]*mu[k];   // E[v^2] - mu^2
            vv = fmaxf(vv, 1e-30f);
            logvarsum += logf(vv);
        }
        const float cost = S * (16.f*beta_u[o] + 0.5f*logvarsum);
        const float x = lamb * (beta_a[o] - cost);

        const int tid = b*32 + o;
        out[tid] = 1.f / (1.f + expf(-x));                      // a (64,32)
        #pragma unroll
        for (int k = 0; k < 16; ++k)
            out[BATCH*OUT_UNITS + tid*16 + k] = mu[k];          // mu (64,32,16)
    }
}

extern "C" void kernel_launch(void* const* d_in, const int* in_sizes, int n_in,
                              void* d_out, int out_size, void* d_ws, size_t ws_size,
                              hipStream_t stream)
{
    const float* a_in = (const float*)d_in[0];
    const float* Mm   = (const float*)d_in[1];
    const float* Wg   = (const float*)d_in[2];
    const float* bu   = (const float*)d_in[3];
    const float* ba   = (const float*)d_in[4];
    float* out = (float*)d_out;

    char* ws = (char*)d_ws;
    size_t off = 0;
    float* partA = (float*)(ws + off); off += (size_t)BATCH*NCHK*PBLK*sizeof(float);
    float* partB = (float*)(ws + off); off += (size_t)BATCH*NCHK*PBLK*sizeof(float);
    float* Wt    = (float*)(ws + off); off += (size_t)IN_UNITS*OUT_UNITS*16*sizeof(float);

    dim3 grid(NCHK, BATCH), blk(256);
    const float4* Wt4 = (const float4*)Wt;

    w_transpose<<<IN_UNITS*512/256, 256, 0, stream>>>(Wg, Wt);
    // it 0: stats under R = a/32 -> partA
    caps_main<0><<<grid, blk, 0, stream>>>(a_in, Mm, Wt4,
                                           nullptr, bu, ba, 0.f, partA);
    // it 1: finalize(partA, lamb0) + R-update + stats -> partB
    caps_main<1><<<grid, blk, 0, stream>>>(a_in, Mm, Wt4,
                                           partA, bu, ba, 0.01f, partB);
    // it 2: finalize(partB, lamb1) + R-update + stats -> partA
    caps_main<1><<<grid, blk, 0, stream>>>(a_in, Mm, Wt4,
                                           partB, bu, ba, 0.012f, partA);
    // output: finalize(partA, lamb2) -> a, mu
    caps_out<<<BATCH, 256, 0, stream>>>(partA, bu, ba, 0.0144f, out);
}